// Round 1
// baseline (419.203 us; speedup 1.0000x reference)
//
#include <hip/hip_runtime.h>
#include <hip/hip_bf16.h>

// Problem: out[token][o] = scale * sum_k x[token][k]*W[o][k]  - scale*zp*sum_k x[token][k] + bias[o]
// M=128 tokens, K=4096, N=16384. Weight int32 = 256 MiB -> memory-bound (~44us floor).
// Strategy: bf16 MFMA (weights exact in bf16), weights global->VGPR direct (no LDS, no
// K-loop barriers), x pre-packed fragment-major bf16 in ws, in-block K-split for 4 waves/CU.

#define IN_F 4096
#define OUT_F 16384
#define NTOK 128

typedef __attribute__((ext_vector_type(8))) short bf16x8;
typedef __attribute__((ext_vector_type(4))) float f32x4;

__device__ __forceinline__ unsigned short f32_to_bf16_rne(float f) {
  unsigned u = __float_as_uint(f);
  u += 0x7fffu + ((u >> 16) & 1u);
  return (unsigned short)(u >> 16);
}

// Pack x [128][4096] f32 -> bf16 fragment-major image in ws, plus per-token sums.
// Image: chunk(s, t, lane) at uint4 index s*512 + t*64 + lane holds
//   x[token = t*16 + (lane&15)][k = s*32 + (lane>>4)*8 + j], j=0..7 (bf16, low-to-high).
__global__ __launch_bounds__(512) void prep_x(const float* __restrict__ x,
                                              uint4* __restrict__ xf,
                                              float* __restrict__ xsum) {
  const int token = blockIdx.x;   // 0..127
  const int i = (int)threadIdx.x; // 0..511, handles k = i*8 .. i*8+7
  const int k0 = i << 3;
  const float4 v0 = *(const float4*)(x + token * IN_F + k0);
  const float4 v1 = *(const float4*)(x + token * IN_F + k0 + 4);
  float v[8] = {v0.x, v0.y, v0.z, v0.w, v1.x, v1.y, v1.z, v1.w};
  unsigned short h[8];
  float s = 0.f;
#pragma unroll
  for (int j = 0; j < 8; ++j) {
    s += v[j];
    h[j] = f32_to_bf16_rne(v[j]);
  }
  uint4 o;
  o.x = (unsigned)h[0] | ((unsigned)h[1] << 16);
  o.y = (unsigned)h[2] | ((unsigned)h[3] << 16);
  o.z = (unsigned)h[4] | ((unsigned)h[5] << 16);
  o.w = (unsigned)h[6] | ((unsigned)h[7] << 16);
  const int slab = i >> 2;          // k0/32
  const int q = i & 3;              // (k0%32)/8
  const int lane = (q << 4) | (token & 15);
  xf[slab * 512 + (token >> 4) * 64 + lane] = o;

  // per-token sum (for zero-point term)
#pragma unroll
  for (int off = 32; off > 0; off >>= 1) s += __shfl_down(s, off, 64);
  __shared__ float wsum[8];
  if ((i & 63) == 0) wsum[i >> 6] = s;
  __syncthreads();
  if (i == 0) {
    float t = 0.f;
#pragma unroll
    for (int a = 0; a < 8; ++a) t += wsum[a];
    xsum[token] = t;
  }
}

// Main GEMM. Grid 256 blocks x 256 threads (4 waves).
// Block covers 64 output features. wave = (kh<<1)|rg:
//   rg selects 32-feature row-group (2 MFMA N-tiles), kh selects K half (2048 each).
// Per wave per K-step(32): 2 A-frag loads (global->VGPR, cvt int->bf16), 8 B-frag loads
// (frag-major image, coalesced), 16 MFMA. Register ping-pong double-buffer, no barriers.
__global__ __launch_bounds__(256, 1) void qlinear_main(
    const int* __restrict__ W, const uint4* __restrict__ xf,
    const float* __restrict__ xsum, const float* __restrict__ scale_p,
    const float* __restrict__ zp_p, const float* __restrict__ bias,
    float* __restrict__ out) {
  __shared__ float red[2 * 64 * 64];  // [rg][frag 0..63][lane] = 32 KB, epilogue only

  const int tid = (int)threadIdx.x;
  const int wave = tid >> 6;
  const int l = tid & 63;
  const int q = l >> 4;   // 0..3
  const int r = l & 15;   // A: weight row-in-tile; D: token-in-tile
  const int rg = wave & 1;
  const int kh = wave >> 1;
  const int o_base = (int)blockIdx.x * 64 + rg * 32;

  const int* Wp0 = W + (o_base + r) * IN_F + kh * 2048 + q * 8;
  const int* Wp1 = W + (o_base + 16 + r) * IN_F + kh * 2048 + q * 8;
  const uint4* xp = xf + kh * 64 * 512 + l;

  f32x4 acc[2][8];
#pragma unroll
  for (int n = 0; n < 2; ++n)
#pragma unroll
    for (int t = 0; t < 8; ++t) acc[n][t] = (f32x4)0.0f;

  int4 a0A, a0B, a1A, a1B;  // buf0: [tile0 lo, tile0 hi, tile1 lo, tile1 hi]
  int4 c0A, c0B, c1A, c1B;  // buf1
  uint4 b0[8], b1[8];

  // prefetch s=0 into buf0
  a0A = *(const int4*)(Wp0);
  a0B = *(const int4*)(Wp0 + 4);
  a1A = *(const int4*)(Wp1);
  a1B = *(const int4*)(Wp1 + 4);
#pragma unroll
  for (int t = 0; t < 8; ++t) b0[t] = xp[t * 64];

  for (int s = 0; s < 64; s += 2) {
    // prefetch s+1 -> buf1 (s+1 <= 63, always in bounds)
    {
      const int sp = s + 1;
      c0A = *(const int4*)(Wp0 + sp * 32);
      c0B = *(const int4*)(Wp0 + sp * 32 + 4);
      c1A = *(const int4*)(Wp1 + sp * 32);
      c1B = *(const int4*)(Wp1 + sp * 32 + 4);
#pragma unroll
      for (int t = 0; t < 8; ++t) b1[t] = xp[sp * 512 + t * 64];
    }
    // compute buf0 (step s)
    {
      bf16x8 af0, af1;
      af0[0] = (short)(__float_as_uint((float)a0A.x) >> 16);
      af0[1] = (short)(__float_as_uint((float)a0A.y) >> 16);
      af0[2] = (short)(__float_as_uint((float)a0A.z) >> 16);
      af0[3] = (short)(__float_as_uint((float)a0A.w) >> 16);
      af0[4] = (short)(__float_as_uint((float)a0B.x) >> 16);
      af0[5] = (short)(__float_as_uint((float)a0B.y) >> 16);
      af0[6] = (short)(__float_as_uint((float)a0B.z) >> 16);
      af0[7] = (short)(__float_as_uint((float)a0B.w) >> 16);
      af1[0] = (short)(__float_as_uint((float)a1A.x) >> 16);
      af1[1] = (short)(__float_as_uint((float)a1A.y) >> 16);
      af1[2] = (short)(__float_as_uint((float)a1A.z) >> 16);
      af1[3] = (short)(__float_as_uint((float)a1A.w) >> 16);
      af1[4] = (short)(__float_as_uint((float)a1B.x) >> 16);
      af1[5] = (short)(__float_as_uint((float)a1B.y) >> 16);
      af1[6] = (short)(__float_as_uint((float)a1B.z) >> 16);
      af1[7] = (short)(__float_as_uint((float)a1B.w) >> 16);
#pragma unroll
      for (int t = 0; t < 8; ++t) {
        bf16x8 bf = *(const bf16x8*)&b0[t];
        acc[0][t] = __builtin_amdgcn_mfma_f32_16x16x32_bf16(af0, bf, acc[0][t], 0, 0, 0);
        acc[1][t] = __builtin_amdgcn_mfma_f32_16x16x32_bf16(af1, bf, acc[1][t], 0, 0, 0);
      }
    }
    // prefetch s+2 -> buf0 (clamped; redundant final load stays in bounds)
    {
      const int sp = (s + 2 < 64) ? (s + 2) : 63;
      a0A = *(const int4*)(Wp0 + sp * 32);
      a0B = *(const int4*)(Wp0 + sp * 32 + 4);
      a1A = *(const int4*)(Wp1 + sp * 32);
      a1B = *(const int4*)(Wp1 + sp * 32 + 4);
#pragma unroll
      for (int t = 0; t < 8; ++t) b0[t] = xp[sp * 512 + t * 64];
    }
    // compute buf1 (step s+1)
    {
      bf16x8 af0, af1;
      af0[0] = (short)(__float_as_uint((float)c0A.x) >> 16);
      af0[1] = (short)(__float_as_uint((float)c0A.y) >> 16);
      af0[2] = (short)(__float_as_uint((float)c0A.z) >> 16);
      af0[3] = (short)(__float_as_uint((float)c0A.w) >> 16);
      af0[4] = (short)(__float_as_uint((float)c0B.x) >> 16);
      af0[5] = (short)(__float_as_uint((float)c0B.y) >> 16);
      af0[6] = (short)(__float_as_uint((float)c0B.z) >> 16);
      af0[7] = (short)(__float_as_uint((float)c0B.w) >> 16);
      af1[0] = (short)(__float_as_uint((float)c1A.x) >> 16);
      af1[1] = (short)(__float_as_uint((float)c1A.y) >> 16);
      af1[2] = (short)(__float_as_uint((float)c1A.z) >> 16);
      af1[3] = (short)(__float_as_uint((float)c1A.w) >> 16);
      af1[4] = (short)(__float_as_uint((float)c1B.x) >> 16);
      af1[5] = (short)(__float_as_uint((float)c1B.y) >> 16);
      af1[6] = (short)(__float_as_uint((float)c1B.z) >> 16);
      af1[7] = (short)(__float_as_uint((float)c1B.w) >> 16);
#pragma unroll
      for (int t = 0; t < 8; ++t) {
        bf16x8 bf = *(const bf16x8*)&b1[t];
        acc[0][t] = __builtin_amdgcn_mfma_f32_16x16x32_bf16(af0, bf, acc[0][t], 0, 0, 0);
        acc[1][t] = __builtin_amdgcn_mfma_f32_16x16x32_bf16(af1, bf, acc[1][t], 0, 0, 0);
      }
    }
  }

  // ---- combine K-halves through LDS, apply scale/zp/bias, store ----
  if (kh == 1) {
#pragma unroll
    for (int n = 0; n < 2; ++n)
#pragma unroll
      for (int t = 0; t < 8; ++t)
#pragma unroll
        for (int e = 0; e < 4; ++e)
          red[rg * 4096 + ((n * 8 + t) * 4 + e) * 64 + l] = acc[n][t][e];
  }
  __syncthreads();
  if (kh == 0) {
    const float scale = *scale_p;
    const float zp = *zp_p;
    const float czp = scale * zp;
    float4 bv0 = *(const float4*)(bias + o_base + q * 4);
    float4 bv1 = *(const float4*)(bias + o_base + 16 + q * 4);
#pragma unroll
    for (int t = 0; t < 8; ++t) {
      const int token = t * 16 + r;           // D: col = lane&15 -> token
      const float corr = -czp * xsum[token];
      float* orow = out + token * OUT_F + o_base + q * 4;  // D: row = q*4+e -> feature
#pragma unroll
      for (int n = 0; n < 2; ++n) {
        const int base = rg * 4096 + ((n * 8 + t) * 4) * 64 + l;
        float4 o;
        o.x = (acc[n][t][0] + red[base + 0 * 64]) * scale + corr;
        o.y = (acc[n][t][1] + red[base + 1 * 64]) * scale + corr;
        o.z = (acc[n][t][2] + red[base + 2 * 64]) * scale + corr;
        o.w = (acc[n][t][3] + red[base + 3 * 64]) * scale + corr;
        if (n == 0) {
          o.x += bv0.x; o.y += bv0.y; o.z += bv0.z; o.w += bv0.w;
        } else {
          o.x += bv1.x; o.y += bv1.y; o.z += bv1.z; o.w += bv1.w;
        }
        *(float4*)(orow + n * 16) = o;
      }
    }
  }
}

extern "C" void kernel_launch(void* const* d_in, const int* in_sizes, int n_in,
                              void* d_out, int out_size, void* d_ws, size_t ws_size,
                              hipStream_t stream) {
  const float* x = (const float*)d_in[0];        // [8,16,4096] f32
  const int* W = (const int*)d_in[1];            // [16384,4096] int32
  const float* scale = (const float*)d_in[2];    // scalar
  const float* zp = (const float*)d_in[3];       // scalar
  const float* bias = (const float*)d_in[4];     // [16384] f32
  float* out = (float*)d_out;                    // [8,16,16384] f32

  uint4* xf = (uint4*)d_ws;                              // 1 MiB bf16 frag image
  float* xsum = (float*)((char*)d_ws + (1 << 20));       // 128 floats

  prep_x<<<NTOK, 512, 0, stream>>>(x, xf, xsum);
  qlinear_main<<<OUT_F / 64, 256, 0, stream>>>(W, xf, xsum, scale, zp, bias, out);
}

// Round 3
// 378.818 us; speedup vs baseline: 1.1066x; 1.1066x over previous
//
#include <hip/hip_runtime.h>
#include <hip/hip_bf16.h>

// out[token][o] = scale * sum_k x[token][k]*W[o][k] - scale*zp*sum_k x[token][k] + bias[o]
// M=128, K=4096, N=16384. W int32 = 256 MiB -> memory-bound (~44us floor @6.3TB/s).
// v3 = v2 with the grid bug fixed: block covers 32 rows -> grid must be OUT_F/32 = 512.
// Coalesced W streaming via LDS transpose (global int4 -> ds_write_b128 -> ds_read_b128),
// 4 waves = 4 K-quarters (no K-loop barriers, wave-private LDS regions),
// block-rotated K start for channel spread, end-of-kernel LDS reduction across waves.

#define IN_F 4096
#define OUT_F 16384
#define NTOK 128

typedef __attribute__((ext_vector_type(8))) short bf16x8;
typedef __attribute__((ext_vector_type(4))) float f32x4;

__device__ __forceinline__ unsigned short f32_to_bf16_rne(float f) {
  unsigned u = __float_as_uint(f);
  u += 0x7fffu + ((u >> 16) & 1u);
  return (unsigned short)(u >> 16);
}

// Pack x [128][4096] f32 -> bf16 fragment-major image in ws, plus per-token sums.
// chunk(s, t, lane) at uint4 index s*512 + t*64 + lane holds
//   x[token = t*16 + (lane&15)][k = s*32 + (lane>>4)*8 + j], j=0..7.
__global__ __launch_bounds__(512) void prep_x(const float* __restrict__ x,
                                              uint4* __restrict__ xf,
                                              float* __restrict__ xsum) {
  const int token = blockIdx.x;   // 0..127
  const int i = (int)threadIdx.x; // 0..511, handles k = i*8 .. i*8+7
  const int k0 = i << 3;
  const float4 v0 = *(const float4*)(x + token * IN_F + k0);
  const float4 v1 = *(const float4*)(x + token * IN_F + k0 + 4);
  float v[8] = {v0.x, v0.y, v0.z, v0.w, v1.x, v1.y, v1.z, v1.w};
  unsigned short h[8];
  float s = 0.f;
#pragma unroll
  for (int j = 0; j < 8; ++j) {
    s += v[j];
    h[j] = f32_to_bf16_rne(v[j]);
  }
  uint4 o;
  o.x = (unsigned)h[0] | ((unsigned)h[1] << 16);
  o.y = (unsigned)h[2] | ((unsigned)h[3] << 16);
  o.z = (unsigned)h[4] | ((unsigned)h[5] << 16);
  o.w = (unsigned)h[6] | ((unsigned)h[7] << 16);
  const int slab = i >> 2;
  const int q = i & 3;
  const int lane = (q << 4) | (token & 15);
  xf[slab * 512 + (token >> 4) * 64 + lane] = o;

#pragma unroll
  for (int off = 32; off > 0; off >>= 1) s += __shfl_down(s, off, 64);
  __shared__ float wsum[8];
  if ((i & 63) == 0) wsum[i >> 6] = s;
  __syncthreads();
  if (i == 0) {
    float t = 0.f;
#pragma unroll
    for (int a = 0; a < 8; ++a) t += wsum[a];
    xsum[token] = t;
  }
}

// int32 in [-127,127] -> f32 has zero low 16 bits -> truncation to bf16 is EXACT.
__device__ __forceinline__ bf16x8 cvt8(int4 a, int4 b) {
  bf16x8 o;
  o[0] = (short)(__float_as_uint((float)a.x) >> 16);
  o[1] = (short)(__float_as_uint((float)a.y) >> 16);
  o[2] = (short)(__float_as_uint((float)a.z) >> 16);
  o[3] = (short)(__float_as_uint((float)a.w) >> 16);
  o[4] = (short)(__float_as_uint((float)b.x) >> 16);
  o[5] = (short)(__float_as_uint((float)b.y) >> 16);
  o[6] = (short)(__float_as_uint((float)b.z) >> 16);
  o[7] = (short)(__float_as_uint((float)b.w) >> 16);
  return o;
}

// Block: 32 output rows. Wave w = K-quarter (1024 ints = 32 k-steps of 32).
// Per k-step per wave: 4 coalesced int4 W-loads (8 rows x 128B each instr),
// ds_write_b128 into private 4KB buffer (dbuf), ds_read_b128 fragments,
// cvt int->bf16 (exact), 16 MFMA (2 row-tiles x 8 token-tiles). No barriers in loop.
__global__ __launch_bounds__(256, 2) void qlinear_main(
    const int* __restrict__ W, const uint4* __restrict__ xf,
    const float* __restrict__ xsum, const float* __restrict__ scale_p,
    const float* __restrict__ zp_p, const float* __restrict__ bias,
    float* __restrict__ out) {
  __shared__ int smem[16384];  // 64 KB: staging = first 32 KB (wave w at w*2048 ints,
                               // 2 bufs x 1024 ints); partials reuse all 64 KB at end.

  const int tid = (int)threadIdx.x;
  const int w = tid >> 6;   // wave = K-quarter
  const int l = tid & 63;
  const int q = l >> 4;     // 0..3
  const int r = l & 15;     // row-in-tile (A) / token-in-tile (D col)
  const int R0 = (int)blockIdx.x * 32;

  // staging lane geometry: instr i covers rows i*8..i*8+7, 128 B per row
  const int row_l = l >> 3;        // 0..7
  const int col_l = (l & 7) * 4;   // int offset 0..28
  const int* Wl = W + (R0 + row_l) * IN_F + w * 1024 + col_l;
  const uint4* xp = xf + (w * 32) * 512 + l;

  int* const sw = smem + w * 2048;                   // wave staging region (8 KB)
  int* const sdl = sw + row_l * 32 + col_l;          // write base (+p*1024 +i*256)
  const int* const srl0 = sw + r * 32 + q * 8;       // tile0 read base (+p*1024)
  const int* const srl1 = sw + (16 + r) * 32 + q * 8;

  f32x4 acc[2][8];
#pragma unroll
  for (int n = 0; n < 2; ++n)
#pragma unroll
    for (int t = 0; t < 8; ++t) acc[n][t] = (f32x4)0.0f;

  const int kk0 = ((int)blockIdx.x * 7) & 31;  // rotate K start per block (channel spread)

  uint4 B0[8], B1[8];
  int4 G0, G1, G2, G3;

  // ---- preamble: stage kk0 -> buf0, B(kk0) -> B0 ----
  {
    const int kk = kk0;
    G0 = *(const int4*)(Wl + kk * 32);
    G1 = *(const int4*)(Wl + 8 * IN_F + kk * 32);
    G2 = *(const int4*)(Wl + 16 * IN_F + kk * 32);
    G3 = *(const int4*)(Wl + 24 * IN_F + kk * 32);
#pragma unroll
    for (int t = 0; t < 8; ++t) B0[t] = xp[kk * 512 + t * 64];
    *(int4*)(sdl + 0) = G0;
    *(int4*)(sdl + 256) = G1;
    *(int4*)(sdl + 512) = G2;
    *(int4*)(sdl + 768) = G3;
  }

  for (int it = 0; it < 16; ++it) {
    const int i2 = it * 2;
    const int kkB = (kk0 + i2 + 1) & 31;
    const int kkC = (kk0 + i2 + 2) & 31;

    // prefetch kkB (VGPR), B(kkB)
    G0 = *(const int4*)(Wl + kkB * 32);
    G1 = *(const int4*)(Wl + 8 * IN_F + kkB * 32);
    G2 = *(const int4*)(Wl + 16 * IN_F + kkB * 32);
    G3 = *(const int4*)(Wl + 24 * IN_F + kkB * 32);
#pragma unroll
    for (int t = 0; t < 8; ++t) B1[t] = xp[kkB * 512 + t * 64];

    // compute step kkA from buf0 + B0
    {
      int4 x0 = *(const int4*)(srl0);
      int4 x1 = *(const int4*)(srl0 + 4);
      int4 y0 = *(const int4*)(srl1);
      int4 y1 = *(const int4*)(srl1 + 4);
      bf16x8 a0 = cvt8(x0, x1);
      bf16x8 a1 = cvt8(y0, y1);
#pragma unroll
      for (int t = 0; t < 8; ++t) {
        bf16x8 bf = *(const bf16x8*)&B0[t];
        acc[0][t] = __builtin_amdgcn_mfma_f32_16x16x32_bf16(a0, bf, acc[0][t], 0, 0, 0);
        acc[1][t] = __builtin_amdgcn_mfma_f32_16x16x32_bf16(a1, bf, acc[1][t], 0, 0, 0);
      }
    }
    // stash kkB -> buf1
    *(int4*)(sdl + 1024) = G0;
    *(int4*)(sdl + 1024 + 256) = G1;
    *(int4*)(sdl + 1024 + 512) = G2;
    *(int4*)(sdl + 1024 + 768) = G3;

    if (it != 15) {  // prefetch kkC (VGPR), B(kkC)
      G0 = *(const int4*)(Wl + kkC * 32);
      G1 = *(const int4*)(Wl + 8 * IN_F + kkC * 32);
      G2 = *(const int4*)(Wl + 16 * IN_F + kkC * 32);
      G3 = *(const int4*)(Wl + 24 * IN_F + kkC * 32);
#pragma unroll
      for (int t = 0; t < 8; ++t) B0[t] = xp[kkC * 512 + t * 64];
    }

    // compute step kkB from buf1 + B1
    {
      int4 x0 = *(const int4*)(srl0 + 1024);
      int4 x1 = *(const int4*)(srl0 + 1024 + 4);
      int4 y0 = *(const int4*)(srl1 + 1024);
      int4 y1 = *(const int4*)(srl1 + 1024 + 4);
      bf16x8 a0 = cvt8(x0, x1);
      bf16x8 a1 = cvt8(y0, y1);
#pragma unroll
      for (int t = 0; t < 8; ++t) {
        bf16x8 bf = *(const bf16x8*)&B1[t];
        acc[0][t] = __builtin_amdgcn_mfma_f32_16x16x32_bf16(a0, bf, acc[0][t], 0, 0, 0);
        acc[1][t] = __builtin_amdgcn_mfma_f32_16x16x32_bf16(a1, bf, acc[1][t], 0, 0, 0);
      }
    }
    if (it != 15) {  // stash kkC -> buf0
      *(int4*)(sdl + 0) = G0;
      *(int4*)(sdl + 256) = G1;
      *(int4*)(sdl + 512) = G2;
      *(int4*)(sdl + 768) = G3;
    }
  }

  // ---- reduce 4 K-quarter partials through LDS, epilogue, store ----
  __syncthreads();  // staging regions become partial regions
  {
    float* sp = (float*)smem;
#pragma unroll
    for (int n = 0; n < 2; ++n)
#pragma unroll
      for (int t = 0; t < 8; ++t)
        *(f32x4*)(sp + w * 4096 + (n * 8 + t) * 256 + l * 4) = acc[n][t];
  }
  __syncthreads();
  const float scale = *scale_p;
  const float zp = *zp_p;
  const float czp = scale * zp;
  const float* sp = (const float*)smem;
#pragma unroll
  for (int j = 0; j < 4; ++j) {
    const int c = w * 4 + j;   // combo = n*8 + t; each wave reduces 4 of 16
    const int n = c >> 3;
    const int t = c & 7;
    f32x4 s0 = *(const f32x4*)(sp + 0 * 4096 + c * 256 + l * 4);
    f32x4 s1 = *(const f32x4*)(sp + 1 * 4096 + c * 256 + l * 4);
    f32x4 s2 = *(const f32x4*)(sp + 2 * 4096 + c * 256 + l * 4);
    f32x4 s3 = *(const f32x4*)(sp + 3 * 4096 + c * 256 + l * 4);
    f32x4 s = (s0 + s1) + (s2 + s3);
    const int token = t * 16 + r;           // D: col = lane&15 -> token
    const float corr = -czp * xsum[token];
    const int feat = R0 + n * 16 + q * 4;   // D: row = q*4+e -> feature
    const float4 bv = *(const float4*)(bias + feat);
    float4 o;
    o.x = s[0] * scale + corr + bv.x;
    o.y = s[1] * scale + corr + bv.y;
    o.z = s[2] * scale + corr + bv.z;
    o.w = s[3] * scale + corr + bv.w;
    *(float4*)(out + token * OUT_F + feat) = o;
  }
}

extern "C" void kernel_launch(void* const* d_in, const int* in_sizes, int n_in,
                              void* d_out, int out_size, void* d_ws, size_t ws_size,
                              hipStream_t stream) {
  const float* x = (const float*)d_in[0];        // [8,16,4096] f32
  const int* W = (const int*)d_in[1];            // [16384,4096] int32
  const float* scale = (const float*)d_in[2];    // scalar
  const float* zp = (const float*)d_in[3];       // scalar
  const float* bias = (const float*)d_in[4];     // [16384] f32
  float* out = (float*)d_out;                    // [8,16,16384] f32

  uint4* xf = (uint4*)d_ws;                              // 1 MiB bf16 frag image
  float* xsum = (float*)((char*)d_ws + (1 << 20));       // 128 floats

  prep_x<<<NTOK, 512, 0, stream>>>(x, xf, xsum);
  // Block covers 32 output rows -> grid = OUT_F/32 = 512 blocks (v2 bug: was /64).
  qlinear_main<<<OUT_F / 32, 256, 0, stream>>>(W, xf, xsum, scale, zp, bias, out);
}

// Round 4
// 370.279 us; speedup vs baseline: 1.1321x; 1.0231x over previous
//
#include <hip/hip_runtime.h>
#include <hip/hip_bf16.h>

// out[token][o] = scale * sum_k x[token][k]*W[o][k] - scale*zp*sum_k x[token][k] + bias[o]
// M=128, K=4096, N=16384. W int32 = 256 MiB -> memory-bound (~44us floor @6.3TB/s).
// v4: token-split waves (8 waves = 8 token-tiles), W shared via LDS (staged once per
// block, cvt to bf16 at staging), no K-split -> no reduction, acc = 16 VGPRs/wave.
// ~100 VGPR -> 2 blocks/CU x 16 waves (launch_bounds(512,4)), dbuf'd 4-k-step phases,
// W prefetch depth 2, 80B-padded LDS rows (conflict-free frag reads), per-block K rotation.

#define IN_F 4096
#define OUT_F 16384
#define NTOK 128

typedef __attribute__((ext_vector_type(8))) short bf16x8;
typedef __attribute__((ext_vector_type(4))) float f32x4;

__device__ __forceinline__ unsigned short f32_to_bf16_rne(float f) {
  unsigned u = __float_as_uint(f);
  u += 0x7fffu + ((u >> 16) & 1u);
  return (unsigned short)(u >> 16);
}

// Pack x [128][4096] f32 -> bf16 fragment-major image in ws, plus per-token sums.
// chunk(s, t, lane) at uint4 index s*512 + t*64 + lane holds
//   x[token = t*16 + (lane&15)][k = s*32 + (lane>>4)*8 + j], j=0..7.
__global__ __launch_bounds__(512) void prep_x(const float* __restrict__ x,
                                              uint4* __restrict__ xf,
                                              float* __restrict__ xsum) {
  const int token = blockIdx.x;   // 0..127
  const int i = (int)threadIdx.x; // 0..511, handles k = i*8 .. i*8+7
  const int k0 = i << 3;
  const float4 v0 = *(const float4*)(x + token * IN_F + k0);
  const float4 v1 = *(const float4*)(x + token * IN_F + k0 + 4);
  float v[8] = {v0.x, v0.y, v0.z, v0.w, v1.x, v1.y, v1.z, v1.w};
  unsigned short h[8];
  float s = 0.f;
#pragma unroll
  for (int j = 0; j < 8; ++j) {
    s += v[j];
    h[j] = f32_to_bf16_rne(v[j]);
  }
  uint4 o;
  o.x = (unsigned)h[0] | ((unsigned)h[1] << 16);
  o.y = (unsigned)h[2] | ((unsigned)h[3] << 16);
  o.z = (unsigned)h[4] | ((unsigned)h[5] << 16);
  o.w = (unsigned)h[6] | ((unsigned)h[7] << 16);
  const int slab = i >> 2;
  const int q = i & 3;
  const int lane = (q << 4) | (token & 15);
  xf[slab * 512 + (token >> 4) * 64 + lane] = o;

#pragma unroll
  for (int off = 32; off > 0; off >>= 1) s += __shfl_down(s, off, 64);
  __shared__ float wsum[8];
  if ((i & 63) == 0) wsum[i >> 6] = s;
  __syncthreads();
  if (i == 0) {
    float t = 0.f;
#pragma unroll
    for (int a = 0; a < 8; ++a) t += wsum[a];
    xsum[token] = t;
  }
}

// int in [-127,127] -> f32 exact with zero low-16 mantissa -> bf16 truncation is EXACT.
__device__ __forceinline__ void stash4(short* lds_s, int off_s, int4 v) {
  uint2 o;
  o.x = (__float_as_uint((float)v.x) >> 16) | (__float_as_uint((float)v.y) & 0xffff0000u);
  o.y = (__float_as_uint((float)v.z) >> 16) | (__float_as_uint((float)v.w) & 0xffff0000u);
  *(uint2*)(lds_s + off_s) = o;  // off_s in shorts; kk multiple of 4 -> 8B aligned
}

// LDS phase buffer layout (bf16): [s_local 0..3][row 0..31][kk 0..31]
// row stride 40 shorts (80 B, padded from 64 -> conflict-free frag reads),
// s_local stride 1280 shorts (2560 B). Phase = 5120 shorts = 10240 B. Double-buffered.
#define SROW 40
#define SSL 1280
#define SBUF 5120

// Grid 512 blocks x 512 threads (8 waves). Block: 32 output rows x full K.
// Wave w owns token-tile w (16 tokens). Phase = 4 k-steps (128 k = 512 B/row of W).
// Per phase: block stages 16 KB W (2 int4/thread, contiguous 512B rows) -> cvt bf16
// -> LDS; every wave reads the same A-frags (x8 reuse), 1 B-load + 2 ds_read_b128 +
// 2 MFMA per k-step. Two barriers/phase; W prefetch depth 2, B depth 1.
__global__ __launch_bounds__(512, 4) void qlinear_main(
    const int* __restrict__ W, const uint4* __restrict__ xf,
    const float* __restrict__ xsum, const float* __restrict__ scale_p,
    const float* __restrict__ zp_p, const float* __restrict__ bias,
    float* __restrict__ out) {
  __shared__ short smem[2 * SBUF];  // 20480 B

  const int tid = (int)threadIdx.x;
  const int w = tid >> 6;   // wave = token tile 0..7
  const int l = tid & 63;
  const int q = l >> 4;     // 0..3
  const int r = l & 15;     // A: row-in-tile; D: token-in-tile
  const int R0 = (int)blockIdx.x * 32;

  // --- staging geometry: thread t loads 2 int4 (j=0 -> rows 0..15, j=1 -> rows 16..31)
  const int row0 = tid >> 5;            // 0..15
  const int c0 = (tid & 31) * 4;        // int index in 128-int phase row span
  const int sl = c0 >> 5;               // k-step within phase
  const int kk = c0 & 31;
  const int g0 = (R0 + row0) * IN_F + c0;        // + pp*128
  const int g1 = (R0 + row0 + 16) * IN_F + c0;
  const int w0 = sl * SSL + row0 * SROW + kk;          // LDS short offset, j=0
  const int w1 = sl * SSL + (row0 + 16) * SROW + kk;   // j=1

  // --- fragment read offsets (shorts): tile n, lane(q,r), + s*SSL
  const int a0off = r * SROW + q * 8;
  const int a1off = (16 + r) * SROW + q * 8;

  const uint4* xp = xf + w * 64 + l;

  f32x4 acc0 = (f32x4)0.0f, acc1 = (f32x4)0.0f;

  const int p0 = ((int)blockIdx.x * 13) & 31;  // phase rotation (DRAM channel spread)

  int4 WnA, WnB;  // W(phase i+1)
  int4 WfA, WfB;  // W(phase i+2)
  uint4 Bc[4], Bn[4];

  // ---- preamble: stage phase p0 -> buf0; prefetch B(p0), W(p0+1) ----
  {
    const int ppk = p0 * 128;
    int4 t0 = *(const int4*)(W + g0 + ppk);
    int4 t1 = *(const int4*)(W + g1 + ppk);
#pragma unroll
    for (int s = 0; s < 4; ++s) Bc[s] = xp[(p0 * 4 + s) * 512];
    const int pp1k = (((p0 + 1) & 31) * 128);
    WnA = *(const int4*)(W + g0 + pp1k);
    WnB = *(const int4*)(W + g1 + pp1k);
    stash4(smem, w0, t0);
    stash4(smem, w1, t1);
  }
  __syncthreads();

#pragma unroll 1
  for (int it = 0; it < 16; ++it) {
    // ================= phase iA = 2*it : compute buf0, stage -> buf1 ==========
    {
      const int ppf = ((2 * it + 2 + p0) & 31) * 128;   // W prefetch (depth 2)
      WfA = *(const int4*)(W + g0 + ppf);
      WfB = *(const int4*)(W + g1 + ppf);
      const int ppb = (2 * it + 1 + p0) & 31;           // B prefetch (depth 1)
#pragma unroll
      for (int s = 0; s < 4; ++s) Bn[s] = xp[(ppb * 4 + s) * 512];
#pragma unroll
      for (int s = 0; s < 4; ++s) {
        bf16x8 a0 = *(const bf16x8*)(smem + s * SSL + a0off);
        bf16x8 a1 = *(const bf16x8*)(smem + s * SSL + a1off);
        bf16x8 b = *(const bf16x8*)&Bc[s];
        acc0 = __builtin_amdgcn_mfma_f32_16x16x32_bf16(a0, b, acc0, 0, 0, 0);
        acc1 = __builtin_amdgcn_mfma_f32_16x16x32_bf16(a1, b, acc1, 0, 0, 0);
      }
      __syncthreads();
      stash4(smem + SBUF, w0, WnA);
      stash4(smem + SBUF, w1, WnB);
      __syncthreads();
    }
    // ================= phase iB = 2*it+1 : compute buf1, stage -> buf0 ========
    {
      const int ppf = ((2 * it + 3 + p0) & 31) * 128;   // redundant wrap at tail: harmless
      WnA = *(const int4*)(W + g0 + ppf);
      WnB = *(const int4*)(W + g1 + ppf);
      const int ppb = (2 * it + 2 + p0) & 31;
#pragma unroll
      for (int s = 0; s < 4; ++s) Bc[s] = xp[(ppb * 4 + s) * 512];
#pragma unroll
      for (int s = 0; s < 4; ++s) {
        bf16x8 a0 = *(const bf16x8*)(smem + SBUF + s * SSL + a0off);
        bf16x8 a1 = *(const bf16x8*)(smem + SBUF + s * SSL + a1off);
        bf16x8 b = *(const bf16x8*)&Bn[s];
        acc0 = __builtin_amdgcn_mfma_f32_16x16x32_bf16(a0, b, acc0, 0, 0, 0);
        acc1 = __builtin_amdgcn_mfma_f32_16x16x32_bf16(a1, b, acc1, 0, 0, 0);
      }
      __syncthreads();
      stash4(smem, w0, WfA);
      stash4(smem, w1, WfB);
      __syncthreads();
    }
  }

  // ---- epilogue: no reduction (full K per wave). D: col=lane&15 -> token, row=q*4+e.
  const float scale = *scale_p;
  const float zp = *zp_p;
  const int token = w * 16 + r;
  const float corr = -scale * zp * xsum[token];
  float* orow = out + token * OUT_F + R0 + q * 4;
  {
    const float4 bv = *(const float4*)(bias + R0 + q * 4);
    float4 o;
    o.x = acc0[0] * scale + corr + bv.x;
    o.y = acc0[1] * scale + corr + bv.y;
    o.z = acc0[2] * scale + corr + bv.z;
    o.w = acc0[3] * scale + corr + bv.w;
    *(float4*)(orow) = o;
  }
  {
    const float4 bv = *(const float4*)(bias + R0 + 16 + q * 4);
    float4 o;
    o.x = acc1[0] * scale + corr + bv.x;
    o.y = acc1[1] * scale + corr + bv.y;
    o.z = acc1[2] * scale + corr + bv.z;
    o.w = acc1[3] * scale + corr + bv.w;
    *(float4*)(orow + 16) = o;
  }
}

extern "C" void kernel_launch(void* const* d_in, const int* in_sizes, int n_in,
                              void* d_out, int out_size, void* d_ws, size_t ws_size,
                              hipStream_t stream) {
  const float* x = (const float*)d_in[0];        // [8,16,4096] f32
  const int* W = (const int*)d_in[1];            // [16384,4096] int32
  const float* scale = (const float*)d_in[2];    // scalar
  const float* zp = (const float*)d_in[3];       // scalar
  const float* bias = (const float*)d_in[4];     // [16384] f32
  float* out = (float*)d_out;                    // [8,16,16384] f32

  uint4* xf = (uint4*)d_ws;                              // 1 MiB bf16 frag image
  float* xsum = (float*)((char*)d_ws + (1 << 20));       // 128 floats

  prep_x<<<NTOK, 512, 0, stream>>>(x, xf, xsum);
  // Block covers 32 output rows -> grid = OUT_F/32 = 512 blocks of 512 threads.
  qlinear_main<<<OUT_F / 32, 512, 0, stream>>>(W, xf, xsum, scale, zp, bias, out);
}